// Round 22
// baseline (244.951 us; speedup 1.0000x reference)
//
#include <hip/hip_runtime.h>
#include <hip/hip_bf16.h>

#define NTOK 16384
#define HID 7168
#define NEXP 256
#define TOPK 8

#define BT 32                  // tokens per block
#define NIT 112                // K iterations (BK=64)

typedef __bf16 bf16x8 __attribute__((ext_vector_type(8)));
typedef float  f32x16 __attribute__((ext_vector_type(16)));

// Weights, MFMA-fragment-linear (R12-proven layout):
// uint4 idx = ((p8*8 + g)*8 + ks)*64 + lane holds
// B[e = g*32 + (lane&31)][k = p8*128 + ks*16 + (lane>>5)*8 .. +8]
__device__ __align__(16) unsigned short g_wb[NEXP * HID];

__device__ __forceinline__ unsigned int f2bfb(float x) {
    unsigned int u = __float_as_uint(x);
    return (u + 0x7fffu + ((u >> 16) & 1u)) >> 16;
}
__device__ __forceinline__ uint4 pk4(float4 p, float4 q) {
    uint4 u;
    u.x = f2bfb(p.x) | (f2bfb(p.y) << 16);
    u.y = f2bfb(p.z) | (f2bfb(p.w) << 16);
    u.z = f2bfb(q.x) | (f2bfb(q.y) << 16);
    u.w = f2bfb(q.z) | (f2bfb(q.w) << 16);
    return u;
}
__device__ __forceinline__ bf16x8 asbf8(uint4 u) {
    union { uint4 a; bf16x8 b; } c; c.a = u; return c.b;
}

__global__ void wconv_frag(const float* __restrict__ wt) {
    const int tid = blockIdx.x * 256 + threadIdx.x;
    const int l  = tid & 63;
    const int ks = (tid >> 6) & 7;
    const int g  = (tid >> 9) & 7;
    const int p  = tid >> 12;
    const int e  = g * 32 + (l & 31);
    const int kb = p * 128 + ks * 16 + ((l >> 5) << 3);
    const float4* s = (const float4*)(wt + (size_t)e * HID + kb);
    ((uint4*)g_wb)[tid] = pk4(s[0], s[1]);
}

__global__ void moe_rows(float* __restrict__ ob) {
    const int q = blockIdx.x * 256 + threadIdx.x;
    ob[262144 + q] = (float)((q & 7) * NTOK + (q >> 3));
}

// lgkm-only barrier: LDS writes visible; global loads stay in flight.
// Safe here because the A tri-buffer separates ds_write from the matching
// ds_read by two barriers, and all global data is read-only.
__device__ __forceinline__ void softbar() {
    asm volatile("s_waitcnt lgkmcnt(0)" ::: "memory");
    __builtin_amdgcn_s_barrier();
    __builtin_amdgcn_sched_barrier(0);
}

// Block 512 thr = 8 waves; wave w: 32 tokens x experts [w*32, w*32+32).
// A: LDS bf16 tri-buffer 3 x 4 KB. B: regs from fragment-linear g_wb.
// Identical to R21's v15 except in-loop barriers are lgkm-only (no vmcnt drain).
__global__ __launch_bounds__(512, 4) void moe_gate_v22(
    const float* __restrict__ hs,
    float* __restrict__ ob)
{
    __shared__ __align__(16) char smem[33792];

    const int tid   = threadIdx.x;
    const int lane  = tid & 63;
    const int w     = tid >> 6;       // 0..7 = expert group
    const int khalf = lane >> 5;
    const int t0    = blockIdx.x * BT;

    // A staging: thread loads hs[t0 + (tid>>4)][s*64 + (tid&15)*4 .. +4]
    const int ar = tid >> 4;          // 0..31
    const int ac = tid & 15;          // 0..15
    const float* aload = hs + (size_t)(t0 + ar) * HID + ac * 4;
    const int awb = (ac >> 1) * 512 + ar * 16 + (ac & 1) * 8;   // bf16 dest byte

    // A fragment read: conflict-free contiguous (lanes 0..31 adjacent 16B)
    const int arb = (lane & 31) * 16;

    // B fragment-linear base for this wave's expert group
    const char* const bbase = (const char*)g_wb + w * 8192 + lane * 16;

    f32x16 acc = {};
    uint4 bA0, bA1, bA2, bA3;   // B set A
    uint4 bB0, bB1, bB2, bB3;   // B set B

    char* p0 = smem;            // read buf (iter s)
    char* p1 = smem + 4096;     // iter s+1
    char* p2 = smem + 8192;     // write target (iter s+2)

#define LOADB(SET, S)                                                         \
    do {                                                                      \
        const char* bp = bbase + (size_t)((S) >> 1) * 65536 + ((S) & 1) * 4096; \
        b##SET##0 = *(const uint4*)(bp);                                      \
        b##SET##1 = *(const uint4*)(bp + 1024);                               \
        b##SET##2 = *(const uint4*)(bp + 2048);                               \
        b##SET##3 = *(const uint4*)(bp + 3072);                               \
    } while (0)

#define WRITEA(V, BUF)                                                        \
    do {                                                                      \
        uint2 u;                                                              \
        u.x = f2bfb((V).x) | (f2bfb((V).y) << 16);                            \
        u.y = f2bfb((V).z) | (f2bfb((V).w) << 16);                            \
        *(uint2*)((BUF) + awb) = u;                                           \
    } while (0)

#define COMPUTE(BUF, SET)                                                     \
    do {                                                                      \
        bf16x8 a;                                                             \
        a = *(const bf16x8*)((BUF) + (0 * 2 + khalf) * 512 + arb);            \
        acc = __builtin_amdgcn_mfma_f32_32x32x16_bf16(a, asbf8(b##SET##0), acc, 0, 0, 0); \
        a = *(const bf16x8*)((BUF) + (1 * 2 + khalf) * 512 + arb);            \
        acc = __builtin_amdgcn_mfma_f32_32x32x16_bf16(a, asbf8(b##SET##1), acc, 0, 0, 0); \
        a = *(const bf16x8*)((BUF) + (2 * 2 + khalf) * 512 + arb);            \
        acc = __builtin_amdgcn_mfma_f32_32x32x16_bf16(a, asbf8(b##SET##2), acc, 0, 0, 0); \
        a = *(const bf16x8*)((BUF) + (3 * 2 + khalf) * 512 + arb);            \
        acc = __builtin_amdgcn_mfma_f32_32x32x16_bf16(a, asbf8(b##SET##3), acc, 0, 0, 0); \
    } while (0)

    // ---- prologue: A(0)->p0, A(1)->p1, B(0)->setA ----
    {
        float4 v0 = *(const float4*)(aload);
        float4 v1 = *(const float4*)(aload + 64);
        WRITEA(v0, p0);
        WRITEA(v1, p1);
    }
    LOADB(A, 0);
    softbar();

    // ---- main loop: x2 unrolled; 1 lgkm-barrier/iter; A 2-ahead, B 1-ahead ----
    for (int s = 0; s < NIT; s += 2) {
        // iter s (read p0, set A)
        float4 vA;
        const bool ldA = (s + 2 < NIT);
        if (ldA) vA = *(const float4*)(aload + (size_t)(s + 2) * 64);
        LOADB(B, s + 1);
        COMPUTE(p0, A);
        softbar();
        if (ldA) WRITEA(vA, p2);

        // iter s+1 (read p1, set B)
        float4 vB;
        const bool ldB = (s + 3 < NIT);
        if (ldB) vB = *(const float4*)(aload + (size_t)(s + 3) * 64);
        if (s + 2 < NIT) LOADB(A, s + 2);
        COMPUTE(p1, B);
        softbar();
        if (ldB) WRITEA(vB, p0);

        // rotate: (p0,p1,p2) <- (p2,p0,p1)
        char* t = p2; p2 = p1; p1 = p0; p0 = t;
    }

    __syncthreads();   // full drain once before aliasing smem

    // ---- epilogue: logits [32][257] f32 aliased over smem ----
    float* ll = (float*)smem;
    {
        const int ec = w * 32 + (lane & 31);
        #pragma unroll
        for (int r = 0; r < 16; ++r) {
            const int tok = (r & 3) + 8 * (r >> 2) + 4 * khalf;
            ll[tok * 257 + ec] = acc[r];
        }
    }
    __syncthreads();

    if (tid < BT) {
        const float* lr = ll + tid * 257;
        float bv[TOPK]; int bi8[TOPK];
        #pragma unroll
        for (int k = 0; k < TOPK; ++k) { bv[k] = -1e30f; bi8[k] = 0; }
        for (int e = 0; e < NEXP; ++e) {
            const float v = lr[e];
            if (v > bv[TOPK - 1]) {
                int k = TOPK - 1;
                while (k > 0 && v > bv[k - 1]) {
                    bv[k] = bv[k - 1]; bi8[k] = bi8[k - 1]; --k;
                }
                bv[k] = v; bi8[k] = e;      // strict > : ties keep lower idx
            }
        }
        float ev[TOPK], ssum = 0.f;
        #pragma unroll
        for (int r = 0; r < TOPK; ++r) { ev[r] = expf(bv[r] - bv[0]); ssum += ev[r]; }
        const float inv = 1.0f / ssum;

        const int tg = t0 + tid;
        #pragma unroll
        for (int r = 0; r < TOPK; ++r) {
            ob[(size_t)tg * TOPK + r]          = (float)bi8[r];   // idx
            ob[131072 + (size_t)tg * TOPK + r] = ev[r] * inv;     // weight
        }
    }
#undef LOADB
#undef WRITEA
#undef COMPUTE
}

extern "C" void kernel_launch(void* const* d_in, const int* in_sizes, int n_in,
                              void* d_out, int out_size, void* d_ws, size_t ws_size,
                              hipStream_t stream) {
    const float* hs = (const float*)d_in[0];   // [16384, 7168] f32
    const float* wt = (const float*)d_in[1];   // [256, 7168] f32
    float* ob = (float*)d_out;                 // f32[393216]: idx | weight | row

    wconv_frag<<<dim3(NEXP * HID / 8 / 256), dim3(256), 0, stream>>>(wt);
    moe_gate_v22<<<dim3(NTOK / BT), dim3(512), 0, stream>>>(hs, ob);
    moe_rows<<<dim3(512), dim3(256), 0, stream>>>(ob);
}